// Round 7
// baseline (246.702 us; speedup 1.0000x reference)
//
#include <hip/hip_runtime.h>
#include <hip/hip_bf16.h>

#define S_LEN 4096
#define E_DIM 512
#define D_DIM 64
#define H_NUM 8
#define KSPLIT 4
#define NKT ((S_LEN / KSPLIT) / 64)   // 16 key tiles per flash block
// scale = 1/sqrt(64) * log2(e): scores come out of MFMA already in exp2 domain
#define QSCALE 0.18033688011112042f

typedef short bf16x8 __attribute__((ext_vector_type(8)));
typedef float f32x4 __attribute__((ext_vector_type(4)));
typedef unsigned short u16x8 __attribute__((ext_vector_type(8)));
typedef unsigned short u16x4 __attribute__((ext_vector_type(4)));

__device__ inline unsigned short f2bf(float x) {
    union { float f; unsigned u; } v; v.f = x;
    unsigned r = v.u + 0x7FFFu + ((v.u >> 16) & 1u);
    return (unsigned short)(r >> 16);
}
__device__ inline float bf2f(unsigned short b) {
    union { unsigned u; float f; } v; v.u = ((unsigned)b) << 16;
    return v.f;
}
__device__ inline f32x4 mfma16(bf16x8 a, bf16x8 b, f32x4 c) {
    return __builtin_amdgcn_mfma_f32_16x16x32_bf16(a, b, c, 0, 0, 0);
}
__device__ inline void gl_lds16(const void* g, void* l) {
    __builtin_amdgcn_global_load_lds(
        (const __attribute__((address_space(1))) void*)g,
        (__attribute__((address_space(3))) void*)l, 16, 0, 0);
}
// dst = {bf16(a) lo16, bf16(b) hi16}
__device__ inline unsigned cvtpk(float a, float b) {
    unsigned r;
    asm volatile("v_cvt_pk_bf16_f32 %0, %1, %2" : "=v"(r) : "v"(a), "v"(b));
    return r;
}

// ---------------------------------------------------------------------------
// prepass (merged): blocks [0,2048) = X split; [2048,2816) = W transpose+split
// ---------------------------------------------------------------------------
__global__ __launch_bounds__(256) void prepass_kernel(
    const float* __restrict__ X, const float* __restrict__ Wq,
    const float* __restrict__ Wk, const float* __restrict__ Wv,
    unsigned short* __restrict__ Xhi, unsigned short* __restrict__ Xlo,
    unsigned short* __restrict__ WT)
{
    int bx = blockIdx.x;
    if (bx < 2048) {
        int i = (bx * 256 + threadIdx.x) * 4;
        float4 v = *(const float4*)&X[i];
        float a[4] = {v.x, v.y, v.z, v.w};
        u16x4 hv, lv;
#pragma unroll
        for (int j = 0; j < 4; ++j) {
            unsigned short hb = f2bf(a[j]);
            hv[j] = hb;
            lv[j] = f2bf(a[j] - bf2f(hb));
        }
        *(u16x4*)&Xhi[i] = hv;
        *(u16x4*)&Xlo[i] = lv;
    } else {
        int wid = bx - 2048;             // 0..767
        int z = wid >> 8;
        const float* W = (z == 0) ? Wq : (z == 1) ? Wk : Wv;
        int idx = (wid & 255) * 256 + threadIdx.x;   // 0..65535 = 512*128
        int n = idx >> 7;
        int e = (idx & 127) * 4;
        int hh = n >> 6, d = n & 63;
        unsigned short* Whi = WT + (size_t)z * 2 * 262144;
        unsigned short* Wlo = Whi + 262144;
        u16x4 hv, lv;
#pragma unroll
        for (int j = 0; j < 4; ++j) {
            float v = W[((size_t)hh * E_DIM + e + j) * D_DIM + d];
            unsigned short hb = f2bf(v);
            hv[j] = hb;
            lv[j] = f2bf(v - bf2f(hb));
        }
        *(u16x4*)&Whi[(size_t)n * E_DIM + e] = hv;
        *(u16x4*)&Wlo[(size_t)n * E_DIM + e] = lv;
    }
}

// ---------------------------------------------------------------------------
// proj: C[4096,512] = X @ Wcat per z, 3-term split-bf16 MFMA (fp32-accurate).
// z=2 writes V TRANSPOSED directly: Vt[h][d][s] (8B s-contiguous stores).
// ---------------------------------------------------------------------------
__global__ __launch_bounds__(256) void proj_kernel(
    const unsigned short* __restrict__ Xhi, const unsigned short* __restrict__ Xlo,
    const unsigned short* __restrict__ WT,
    unsigned short* __restrict__ Qhi, unsigned short* __restrict__ Qlo,
    unsigned short* __restrict__ Khi, unsigned short* __restrict__ Klo,
    unsigned short* __restrict__ Vt)
{
    __shared__ __align__(16) unsigned short XhS[128 * 64];
    __shared__ __align__(16) unsigned short XlS[128 * 64];
    __shared__ __align__(16) unsigned short WhS[128 * 64];
    __shared__ __align__(16) unsigned short WlS[128 * 64];

    const int s0 = blockIdx.x * 128, n0 = blockIdx.y * 128, z = blockIdx.z;
    const unsigned short* Wh_g = WT + (size_t)z * 524288;
    const unsigned short* Wl_g = Wh_g + 262144;

    const int tid = threadIdx.x, lane = tid & 63, w = tid >> 6;
    const int l15 = lane & 15, lhi = lane >> 4;
    const int wr = w >> 1, wc = w & 1;

    const int chunk = lane & 7;
    size_t aoff[4], boff[4];
    int ldso[4];
#pragma unroll
    for (int i = 0; i < 4; ++i) {
        int r = w * 32 + i * 8 + (lane >> 3);
        int swz = (chunk * 16) ^ ((r & 7) << 4);
        aoff[i] = ((size_t)(s0 + r)) * 1024 + swz;
        boff[i] = ((size_t)(n0 + r)) * 1024 + swz;
        ldso[i] = (w * 32 + i * 8) * 128;
    }

    f32x4 acc[4][4];
#pragma unroll
    for (int a = 0; a < 4; ++a)
#pragma unroll
        for (int b = 0; b < 4; ++b) acc[a][b] = (f32x4){0.f, 0.f, 0.f, 0.f};

    for (int kb = 0; kb < E_DIM; kb += 64) {
        __syncthreads();
#pragma unroll
        for (int i = 0; i < 4; ++i) {
            size_t ab = aoff[i] + kb * 2;
            size_t bb = boff[i] + kb * 2;
            gl_lds16((const char*)Xhi + ab, (char*)XhS + ldso[i]);
            gl_lds16((const char*)Xlo + ab, (char*)XlS + ldso[i]);
            gl_lds16((const char*)Wh_g + bb, (char*)WhS + ldso[i]);
            gl_lds16((const char*)Wl_g + bb, (char*)WlS + ldso[i]);
        }
        __syncthreads();

#pragma unroll
        for (int kc = 0; kc < 2; ++kc) {
            int cb = kc * 64 + lhi * 16;
            bf16x8 ah[4], al[4], bh[4], bl[4];
#pragma unroll
            for (int rt = 0; rt < 4; ++rt) {
                int row = wr * 64 + rt * 16 + l15;
                int ad = row * 128 + (cb ^ ((row & 7) << 4));
                ah[rt] = *(const bf16x8*)((const char*)XhS + ad);
                al[rt] = *(const bf16x8*)((const char*)XlS + ad);
            }
#pragma unroll
            for (int nt = 0; nt < 4; ++nt) {
                int n = wc * 64 + nt * 16 + l15;
                int bd = n * 128 + (cb ^ ((n & 7) << 4));
                bh[nt] = *(const bf16x8*)((const char*)WhS + bd);
                bl[nt] = *(const bf16x8*)((const char*)WlS + bd);
            }
#pragma unroll
            for (int rt = 0; rt < 4; ++rt)
#pragma unroll
                for (int nt = 0; nt < 4; ++nt) {
                    acc[rt][nt] = mfma16(ah[rt], bh[nt], acc[rt][nt]);
                    acc[rt][nt] = mfma16(ah[rt], bl[nt], acc[rt][nt]);
                    acc[rt][nt] = mfma16(al[rt], bh[nt], acc[rt][nt]);
                }
        }
    }

#pragma unroll
    for (int rt = 0; rt < 4; ++rt)
#pragma unroll
        for (int nt = 0; nt < 4; ++nt) {
            int n = n0 + wc * 64 + nt * 16 + l15;
            int hh = n >> 6, d = n & 63;
            if (z == 2) {
                // transposed V write: s-contiguous 8B
                u16x4 vv;
#pragma unroll
                for (int j = 0; j < 4; ++j) vv[j] = f2bf(acc[rt][nt][j]);
                int sb = s0 + wr * 64 + rt * 16 + lhi * 4;
                *(u16x4*)&Vt[((size_t)(hh * D_DIM + d)) * S_LEN + sb] = vv;
            } else {
#pragma unroll
                for (int j = 0; j < 4; ++j) {
                    int s = s0 + wr * 64 + rt * 16 + lhi * 4 + j;
                    float val = acc[rt][nt][j];
                    size_t o = ((size_t)hh * S_LEN + s) * D_DIM + d;
                    if (z == 0) {
                        val *= QSCALE;
                        unsigned short hb = f2bf(val);
                        Qhi[o] = hb;
                        Qlo[o] = f2bf(val - bf2f(hb));
                    } else {
                        unsigned short hb = f2bf(val);
                        Khi[o] = hb;
                        Klo[o] = f2bf(val - bf2f(hb));
                    }
                }
            }
        }
}

// ---------------------------------------------------------------------------
// flash: swapped QK^T (A=K, B=Q), 16x16 MFMA, DOUBLE-BUFFERED staging (T3
// minimal 2-phase): STAGE(t+1) issued before compute(t); single barrier per
// tile whose implicit vmcnt(0) lands after a full compute phase of latency
// hiding. s_setprio(1) around MFMA clusters (T5).
// ---------------------------------------------------------------------------
__global__ __launch_bounds__(256) void flash_kernel(
    const unsigned short* __restrict__ Qhi, const unsigned short* __restrict__ Qlo,
    const unsigned short* __restrict__ Khi_g, const unsigned short* __restrict__ Klo_g,
    const unsigned short* __restrict__ Vt_g,
    unsigned short* __restrict__ Part, float2* __restrict__ ML)
{
    __shared__ __align__(16) char lds[2][24576];     // per buf: Khi 8K | Klo 8K | Vt 8K
    __shared__ __align__(16) unsigned short PS[4][16 * 64]; // per-wave [row][key]

    const int h  = blockIdx.y;
    const int ks = blockIdx.z;
    const int q0 = blockIdx.x * 64;
    const int tid  = threadIdx.x;
    const int lane = tid & 63;
    const int w    = tid >> 6;
    const int l15  = lane & 15;
    const int lhi  = lane >> 4;

    // Q fragments (B-operand): col = l15 = qrow, k(d) = lhi*8 + 32c + j
    const int qrow = q0 + w * 16 + l15;
    bf16x8 qh[2], ql[2];
#pragma unroll
    for (int c = 0; c < 2; ++c) {
        size_t off = ((size_t)(h * S_LEN + qrow)) * D_DIM + lhi * 8 + 32 * c;
        qh[c] = *(const bf16x8*)&Qhi[off];
        ql[c] = *(const bf16x8*)&Qlo[off];
    }

    // staging source pointers (pre-swizzled within 128B rows)
    const char *pKh[2], *pKl[2], *pV[2];
    int ldsd[2];
    {
        const int chunk = lane & 7;
#pragma unroll
        for (int i = 0; i < 2; ++i) {
            int r = w * 16 + i * 8 + (lane >> 3);
            int swz = (chunk * 16) ^ ((r & 7) << 4);
            size_t kb = ((size_t)(h * S_LEN + ks * (S_LEN / KSPLIT) + r)) * 128 + swz;
            pKh[i] = (const char*)Khi_g + kb;
            pKl[i] = (const char*)Klo_g + kb;
            size_t vb = ((size_t)(h * D_DIM + r) * S_LEN + ks * (S_LEN / KSPLIT)) * 2 + swz;
            pV[i] = (const char*)Vt_g + vb;
            ldsd[i] = (w * 16 + i * 8) * 128;
        }
    }

#define STAGE(B) do {                                            \
        _Pragma("unroll")                                        \
        for (int i = 0; i < 2; ++i) {                            \
            char* base = &lds[(B)][0];                           \
            gl_lds16(pKh[i], base + ldsd[i]);                    \
            gl_lds16(pKl[i], base + 8192 + ldsd[i]);             \
            gl_lds16(pV[i],  base + 16384 + ldsd[i]);            \
            pKh[i] += 8192; pKl[i] += 8192; pV[i] += 128;        \
        }                                                        \
    } while (0)

    f32x4 acc_o[4];
#pragma unroll
    for (int nt = 0; nt < 4; ++nt) acc_o[nt] = (f32x4){0.f, 0.f, 0.f, 0.f};
    float m2 = -1e30f, lsum = 0.f;   // state for q-row l15 (replicated over lhi)

    unsigned short* pw = &PS[w][0];

    STAGE(0);
    __syncthreads();

    int buf = 0;
    for (int kt = 0; kt < NKT; ++kt) {
        if (kt + 1 < NKT) STAGE(buf ^ 1);   // prefetch next tile (in flight during compute)

        const char* Kh = &lds[buf][0];
        const char* Kl = Kh + 8192;
        const char* Vl = Kh + 16384;

        // ---- scores (exp2 domain): 3-term split MFMA, swapped (A=K, B=Q)
        f32x4 sacc[4];
#pragma unroll
        for (int nt = 0; nt < 4; ++nt) sacc[nt] = (f32x4){0.f, 0.f, 0.f, 0.f};
        __builtin_amdgcn_s_setprio(1);
#pragma unroll
        for (int c = 0; c < 2; ++c) {
            int colb = (lhi * 8 + 32 * c) * 2;
#pragma unroll
            for (int nt = 0; nt < 4; ++nt) {
                int key = l15 + 16 * nt;      // A row = key within tile
                int lo = key * 128 + (((colb >> 4) ^ (key & 7)) << 4);
                bf16x8 kh = *(const bf16x8*)(Kh + lo);
                bf16x8 kl = *(const bf16x8*)(Kl + lo);
                sacc[nt] = mfma16(kh, qh[c], sacc[nt]);
                sacc[nt] = mfma16(kl, qh[c], sacc[nt]);
                sacc[nt] = mfma16(kh, ql[c], sacc[nt]);
            }
        }
        __builtin_amdgcn_s_setprio(0);

        // ---- softmax for q-row l15 (16 in-lane scores + 2 shfl)
        float mx0 = fmaxf(fmaxf(sacc[0][0], sacc[0][1]), fmaxf(sacc[0][2], sacc[0][3]));
        float mx1 = fmaxf(fmaxf(sacc[1][0], sacc[1][1]), fmaxf(sacc[1][2], sacc[1][3]));
        float mx2 = fmaxf(fmaxf(sacc[2][0], sacc[2][1]), fmaxf(sacc[2][2], sacc[2][3]));
        float mx3 = fmaxf(fmaxf(sacc[3][0], sacc[3][1]), fmaxf(sacc[3][2], sacc[3][3]));
        float vm = fmaxf(fmaxf(mx0, mx1), fmaxf(mx2, mx3));
        vm = fmaxf(vm, __shfl_xor(vm, 16));
        vm = fmaxf(vm, __shfl_xor(vm, 32));

        // T13 defer-rescale: only rescale when some row's max grew by > 8
        if (!__all(vm <= m2 + 8.f)) {
            float mnew = fmaxf(m2, vm);
            float sc = exp2f(m2 - mnew);
            m2 = mnew;
            lsum *= sc;
            float scj[4];
#pragma unroll
            for (int j = 0; j < 4; ++j) scj[j] = __shfl(sc, lhi * 4 + j);
#pragma unroll
            for (int nt = 0; nt < 4; ++nt)
#pragma unroll
                for (int j = 0; j < 4; ++j) acc_o[nt][j] *= scj[j];
        }

        // ---- e = exp2(s - m2); pack pairs; write 8B per nt (keys 16nt+lhi*4..+4)
        float sum = 0.f;
#pragma unroll
        for (int nt = 0; nt < 4; ++nt) {
            float e0 = exp2f(sacc[nt][0] - m2);
            float e1 = exp2f(sacc[nt][1] - m2);
            float e2 = exp2f(sacc[nt][2] - m2);
            float e3 = exp2f(sacc[nt][3] - m2);
            sum += (e0 + e1) + (e2 + e3);
            int colb = 32 * nt + 8 * lhi;
            int adr = l15 * 128 + ((((colb >> 4)) ^ (l15 & 7)) << 4) + (colb & 15);
            uint2 pk = make_uint2(cvtpk(e0, e1), cvtpk(e2, e3));
            *(uint2*)((char*)pw + adr) = pk;
        }
        sum += __shfl_xor(sum, 16);
        sum += __shfl_xor(sum, 32);
        lsum += sum;

        // ---- PV: A = P[row=l15][k=key], B = V^T[col=d][k=key]
        __builtin_amdgcn_s_setprio(1);
#pragma unroll
        for (int c = 0; c < 2; ++c) {
            int colb = (lhi * 8 + 32 * c) * 2;
            int loA = l15 * 128 + (((colb >> 4) ^ (l15 & 7)) << 4);
            bf16x8 pa = *(const bf16x8*)((const char*)pw + loA);
#pragma unroll
            for (int nt = 0; nt < 4; ++nt) {
                int d = l15 + 16 * nt;
                int loB = d * 128 + (((colb >> 4) ^ (d & 7)) << 4);
                bf16x8 vb = *(const bf16x8*)(Vl + loB);
                acc_o[nt] = mfma16(pa, vb, acc_o[nt]);
            }
        }
        __builtin_amdgcn_s_setprio(0);

        if (kt + 1 < NKT) {
            __syncthreads();   // drains next-tile loads (issued pre-compute) + frees buf
            buf ^= 1;
        }
    }
#undef STAGE

    // ---- epilogue: normalized bf16 partial + (m,l)
    if (lane < 16) {
        ML[(size_t)(ks * H_NUM + h) * S_LEN + q0 + w * 16 + l15] =
            make_float2(m2, lsum);
    }
    unsigned short* PT = Part + ((size_t)(ks * H_NUM + h)) * S_LEN * D_DIM;
#pragma unroll
    for (int r = 0; r < 4; ++r) {
        float lr = __shfl(lsum, lhi * 4 + r);
        float inv = 1.f / lr;
        int s = q0 + w * 16 + lhi * 4 + r;
#pragma unroll
        for (int nt = 0; nt < 4; ++nt)
            PT[(size_t)s * D_DIM + l15 + 16 * nt] = f2bf(acc_o[nt][r] * inv);
    }
}

// ---------------------------------------------------------------------------
// cw: per (h,s) combine weights c_i = l_i*2^(m_i-m) / L  (4 splits)
// ---------------------------------------------------------------------------
__global__ __launch_bounds__(256) void cw_kernel(
    const float2* __restrict__ ML, float4* __restrict__ CW)
{
    int i = blockIdx.x * 256 + threadIdx.x;   // H*S = 32768
    float2 a[KSPLIT];
    float m = -1e30f;
#pragma unroll
    for (int k = 0; k < KSPLIT; ++k) {
        a[k] = ML[(size_t)k * H_NUM * S_LEN + i];
        m = fmaxf(m, a[k].x);
    }
    float wk[KSPLIT], wsum = 0.f;
#pragma unroll
    for (int k = 0; k < KSPLIT; ++k) {
        wk[k] = exp2f(a[k].x - m) * a[k].y;
        wsum += wk[k];
    }
    float inv = 1.f / wsum;
    CW[i] = make_float4(wk[0] * inv, wk[1] * inv, wk[2] * inv, wk[3] * inv);
}

// ---------------------------------------------------------------------------
// zout: Z[4096,64] = combine(4 partials) [4096,512] @ W0[512,64], fp32.
// ---------------------------------------------------------------------------
__global__ __launch_bounds__(256) void zout_kernel(
    const unsigned short* __restrict__ Part, const float4* __restrict__ CW,
    const float* __restrict__ W0, float* __restrict__ Z)
{
    __shared__ __align__(16) float Rs[32][64];
    __shared__ __align__(16) float Ws[32][64];

    const size_t PSZ = (size_t)H_NUM * S_LEN * D_DIM;
    const int s0 = blockIdx.x * 64;
    const int tid = threadIdx.x;
    const int tx = tid & 15;
    const int ty = tid >> 4;

    float acc[4][4];
#pragma unroll
    for (int i = 0; i < 4; ++i)
#pragma unroll
        for (int j = 0; j < 4; ++j) acc[i][j] = 0.f;

    for (int kb = 0; kb < E_DIM; kb += 32) {
        __syncthreads();
#pragma unroll
        for (int p = 0; p < 2; ++p) {
            int idx = tid + 256 * p;
            int row = idx >> 3;
            int kq  = idx & 7;
            int k = kb + kq * 4;
            int hh = k >> 6, d0 = k & 63;
            int s = s0 + row;
            size_t pbase = ((size_t)hh * S_LEN + s) * D_DIM + d0;
            float4 c = *(const float4*)&CW[hh * S_LEN + s];
            u16x4 a0 = *(const u16x4*)&Part[pbase];
            u16x4 a1 = *(const u16x4*)&Part[PSZ + pbase];
            u16x4 a2 = *(const u16x4*)&Part[2 * PSZ + pbase];
            u16x4 a3 = *(const u16x4*)&Part[3 * PSZ + pbase];
#pragma unroll
            for (int j = 0; j < 4; ++j)
                Rs[kq * 4 + j][row] = bf2f(a0[j]) * c.x + bf2f(a1[j]) * c.y +
                                      bf2f(a2[j]) * c.z + bf2f(a3[j]) * c.w;
        }
#pragma unroll
        for (int p = 0; p < 2; ++p) {
            int idx = tid + 256 * p;
            int k  = idx >> 4;
            int nq = idx & 15;
            *(float4*)&Ws[k][nq * 4] = *(const float4*)&W0[(size_t)(kb + k) * D_DIM + nq * 4];
        }
        __syncthreads();

#pragma unroll 8
        for (int k = 0; k < 32; ++k) {
            float a[4], b[4];
            *(float4*)&a[0] = *(const float4*)&Rs[k][ty * 4];
            *(float4*)&b[0] = *(const float4*)&Ws[k][tx * 4];
#pragma unroll
            for (int i = 0; i < 4; ++i)
#pragma unroll
                for (int j = 0; j < 4; ++j) acc[i][j] += a[i] * b[j];
        }
    }

#pragma unroll
    for (int i = 0; i < 4; ++i) {
        float4 o = make_float4(acc[i][0], acc[i][1], acc[i][2], acc[i][3]);
        *(float4*)&Z[(size_t)(s0 + ty * 4 + i) * D_DIM + tx * 4] = o;
    }
}

// ---------------------------------------------------------------------------
extern "C" void kernel_launch(void* const* d_in, const int* in_sizes, int n_in,
                              void* d_out, int out_size, void* d_ws, size_t ws_size,
                              hipStream_t stream) {
    const float* X  = (const float*)d_in[0];
    const float* Wq = (const float*)d_in[1];
    const float* Wk = (const float*)d_in[2];
    const float* Wv = (const float*)d_in[3];
    const float* W0 = (const float*)d_in[4];

    char* ws = (char*)d_ws;
    const size_t MB = 1ull << 20;
    unsigned short* Qhi = (unsigned short*)(ws + 0 * MB);
    unsigned short* Qlo = (unsigned short*)(ws + 4 * MB);
    unsigned short* Khi = (unsigned short*)(ws + 8 * MB);
    unsigned short* Klo = (unsigned short*)(ws + 12 * MB);
    unsigned short* Vt  = (unsigned short*)(ws + 16 * MB);
    // phase-1 region (dead before flash writes Part):
    unsigned short* Xhi = (unsigned short*)(ws + 24 * MB);
    unsigned short* Xlo = (unsigned short*)(ws + 28 * MB);
    unsigned short* WT  = (unsigned short*)(ws + 32 * MB);   // 3 MB
    // phase-2 (aliases phase-1 region):
    unsigned short* Part = (unsigned short*)(ws + 20 * MB);  // 16 MB (4 splits)
    float2* ML = (float2*)(ws + 36 * MB);                    // 1 MB
    float4* CW = (float4*)(ws + 37 * MB);                    // 0.5 MB

    float* Z = (float*)d_out;

    prepass_kernel<<<dim3(2048 + 768), 256, 0, stream>>>(X, Wq, Wk, Wv, Xhi, Xlo, WT);
    proj_kernel<<<dim3(S_LEN / 128, 4, 3), 256, 0, stream>>>(
        Xhi, Xlo, WT, Qhi, Qlo, Khi, Klo, Vt);
    flash_kernel<<<dim3(S_LEN / 64, H_NUM, KSPLIT), 256, 0, stream>>>(
        Qhi, Qlo, Khi, Klo, Vt, Part, ML);
    cw_kernel<<<dim3(H_NUM * S_LEN / 256), 256, 0, stream>>>(ML, CW);
    zout_kernel<<<dim3(S_LEN / 64), 256, 0, stream>>>(Part, CW, W0, Z);
}

// Round 10
// 229.203 us; speedup vs baseline: 1.0763x; 1.0763x over previous
//
#include <hip/hip_runtime.h>
#include <hip/hip_bf16.h>

#define S_LEN 4096
#define E_DIM 512
#define D_DIM 64
#define H_NUM 8
#define KSPLIT 4
#define NKT ((S_LEN / KSPLIT) / 64)   // 16 key tiles per flash block
// scale = 1/sqrt(64) * log2(e): scores come out of MFMA already in exp2 domain
#define QSCALE 0.18033688011112042f

typedef short bf16x8 __attribute__((ext_vector_type(8)));
typedef float f32x4 __attribute__((ext_vector_type(4)));
typedef unsigned short u16x8 __attribute__((ext_vector_type(8)));
typedef unsigned short u16x4 __attribute__((ext_vector_type(4)));

__device__ inline unsigned short f2bf(float x) {
    union { float f; unsigned u; } v; v.f = x;
    unsigned r = v.u + 0x7FFFu + ((v.u >> 16) & 1u);
    return (unsigned short)(r >> 16);
}
__device__ inline float bf2f(unsigned short b) {
    union { unsigned u; float f; } v; v.u = ((unsigned)b) << 16;
    return v.f;
}
__device__ inline f32x4 mfma16(bf16x8 a, bf16x8 b, f32x4 c) {
    return __builtin_amdgcn_mfma_f32_16x16x32_bf16(a, b, c, 0, 0, 0);
}
__device__ inline void gl_lds16(const void* g, void* l) {
    __builtin_amdgcn_global_load_lds(
        (const __attribute__((address_space(1))) void*)g,
        (__attribute__((address_space(3))) void*)l, 16, 0, 0);
}
// dst = {bf16(a) lo16, bf16(b) hi16}
__device__ inline unsigned cvtpk(float a, float b) {
    unsigned r;
    asm volatile("v_cvt_pk_bf16_f32 %0, %1, %2" : "=v"(r) : "v"(a), "v"(b));
    return r;
}

// ---------------------------------------------------------------------------
// prepass (merged): blocks [0,2048) = X split; [2048,2816) = W transpose+split
// ---------------------------------------------------------------------------
__global__ __launch_bounds__(256) void prepass_kernel(
    const float* __restrict__ X, const float* __restrict__ Wq,
    const float* __restrict__ Wk, const float* __restrict__ Wv,
    unsigned short* __restrict__ Xhi, unsigned short* __restrict__ Xlo,
    unsigned short* __restrict__ WT)
{
    int bx = blockIdx.x;
    if (bx < 2048) {
        int i = (bx * 256 + threadIdx.x) * 4;
        float4 v = *(const float4*)&X[i];
        float a[4] = {v.x, v.y, v.z, v.w};
        u16x4 hv, lv;
#pragma unroll
        for (int j = 0; j < 4; ++j) {
            unsigned short hb = f2bf(a[j]);
            hv[j] = hb;
            lv[j] = f2bf(a[j] - bf2f(hb));
        }
        *(u16x4*)&Xhi[i] = hv;
        *(u16x4*)&Xlo[i] = lv;
    } else {
        int wid = bx - 2048;             // 0..767
        int z = wid >> 8;
        const float* W = (z == 0) ? Wq : (z == 1) ? Wk : Wv;
        int idx = (wid & 255) * 256 + threadIdx.x;   // 0..65535 = 512*128
        int n = idx >> 7;
        int e = (idx & 127) * 4;
        int hh = n >> 6, d = n & 63;
        unsigned short* Whi = WT + (size_t)z * 2 * 262144;
        unsigned short* Wlo = Whi + 262144;
        u16x4 hv, lv;
#pragma unroll
        for (int j = 0; j < 4; ++j) {
            float v = W[((size_t)hh * E_DIM + e + j) * D_DIM + d];
            unsigned short hb = f2bf(v);
            hv[j] = hb;
            lv[j] = f2bf(v - bf2f(hb));
        }
        *(u16x4*)&Whi[(size_t)n * E_DIM + e] = hv;
        *(u16x4*)&Wlo[(size_t)n * E_DIM + e] = lv;
    }
}

// ---------------------------------------------------------------------------
// proj: C[4096,512] = X @ Wcat per z, 3-term split-bf16 MFMA (fp32-accurate).
// z=2 writes V TRANSPOSED directly: Vt[h][d][s] (8B s-contiguous stores).
// ---------------------------------------------------------------------------
__global__ __launch_bounds__(256) void proj_kernel(
    const unsigned short* __restrict__ Xhi, const unsigned short* __restrict__ Xlo,
    const unsigned short* __restrict__ WT,
    unsigned short* __restrict__ Qhi, unsigned short* __restrict__ Qlo,
    unsigned short* __restrict__ Khi, unsigned short* __restrict__ Klo,
    unsigned short* __restrict__ Vt)
{
    __shared__ __align__(16) unsigned short XhS[128 * 64];
    __shared__ __align__(16) unsigned short XlS[128 * 64];
    __shared__ __align__(16) unsigned short WhS[128 * 64];
    __shared__ __align__(16) unsigned short WlS[128 * 64];

    const int s0 = blockIdx.x * 128, n0 = blockIdx.y * 128, z = blockIdx.z;
    const unsigned short* Wh_g = WT + (size_t)z * 524288;
    const unsigned short* Wl_g = Wh_g + 262144;

    const int tid = threadIdx.x, lane = tid & 63, w = tid >> 6;
    const int l15 = lane & 15, lhi = lane >> 4;
    const int wr = w >> 1, wc = w & 1;

    const int chunk = lane & 7;
    size_t aoff[4], boff[4];
    int ldso[4];
#pragma unroll
    for (int i = 0; i < 4; ++i) {
        int r = w * 32 + i * 8 + (lane >> 3);
        int swz = (chunk * 16) ^ ((r & 7) << 4);
        aoff[i] = ((size_t)(s0 + r)) * 1024 + swz;
        boff[i] = ((size_t)(n0 + r)) * 1024 + swz;
        ldso[i] = (w * 32 + i * 8) * 128;
    }

    f32x4 acc[4][4];
#pragma unroll
    for (int a = 0; a < 4; ++a)
#pragma unroll
        for (int b = 0; b < 4; ++b) acc[a][b] = (f32x4){0.f, 0.f, 0.f, 0.f};

    for (int kb = 0; kb < E_DIM; kb += 64) {
        __syncthreads();
#pragma unroll
        for (int i = 0; i < 4; ++i) {
            size_t ab = aoff[i] + kb * 2;
            size_t bb = boff[i] + kb * 2;
            gl_lds16((const char*)Xhi + ab, (char*)XhS + ldso[i]);
            gl_lds16((const char*)Xlo + ab, (char*)XlS + ldso[i]);
            gl_lds16((const char*)Wh_g + bb, (char*)WhS + ldso[i]);
            gl_lds16((const char*)Wl_g + bb, (char*)WlS + ldso[i]);
        }
        __syncthreads();

#pragma unroll
        for (int kc = 0; kc < 2; ++kc) {
            int cb = kc * 64 + lhi * 16;
            bf16x8 ah[4], al[4], bh[4], bl[4];
#pragma unroll
            for (int rt = 0; rt < 4; ++rt) {
                int row = wr * 64 + rt * 16 + l15;
                int ad = row * 128 + (cb ^ ((row & 7) << 4));
                ah[rt] = *(const bf16x8*)((const char*)XhS + ad);
                al[rt] = *(const bf16x8*)((const char*)XlS + ad);
            }
#pragma unroll
            for (int nt = 0; nt < 4; ++nt) {
                int n = wc * 64 + nt * 16 + l15;
                int bd = n * 128 + (cb ^ ((n & 7) << 4));
                bh[nt] = *(const bf16x8*)((const char*)WhS + bd);
                bl[nt] = *(const bf16x8*)((const char*)WlS + bd);
            }
#pragma unroll
            for (int rt = 0; rt < 4; ++rt)
#pragma unroll
                for (int nt = 0; nt < 4; ++nt) {
                    acc[rt][nt] = mfma16(ah[rt], bh[nt], acc[rt][nt]);
                    acc[rt][nt] = mfma16(ah[rt], bl[nt], acc[rt][nt]);
                    acc[rt][nt] = mfma16(al[rt], bh[nt], acc[rt][nt]);
                }
        }
    }

#pragma unroll
    for (int rt = 0; rt < 4; ++rt)
#pragma unroll
        for (int nt = 0; nt < 4; ++nt) {
            int n = n0 + wc * 64 + nt * 16 + l15;
            int hh = n >> 6, d = n & 63;
            if (z == 2) {
                // transposed V write: s-contiguous 8B
                u16x4 vv;
#pragma unroll
                for (int j = 0; j < 4; ++j) vv[j] = f2bf(acc[rt][nt][j]);
                int sb = s0 + wr * 64 + rt * 16 + lhi * 4;
                *(u16x4*)&Vt[((size_t)(hh * D_DIM + d)) * S_LEN + sb] = vv;
            } else {
#pragma unroll
                for (int j = 0; j < 4; ++j) {
                    int s = s0 + wr * 64 + rt * 16 + lhi * 4 + j;
                    float val = acc[rt][nt][j];
                    size_t o = ((size_t)hh * S_LEN + s) * D_DIM + d;
                    if (z == 0) {
                        val *= QSCALE;
                        unsigned short hb = f2bf(val);
                        Qhi[o] = hb;
                        Qlo[o] = f2bf(val - bf2f(hb));
                    } else {
                        unsigned short hb = f2bf(val);
                        Khi[o] = hb;
                        Klo[o] = f2bf(val - bf2f(hb));
                    }
                }
            }
        }
}

// ---------------------------------------------------------------------------
// flash: swapped QK^T (A=K, B=Q), 16x16 MFMA, single-buffer staging (r6
// structure), widened to TWO q-groups per wave (rows w*16 and 64+w*16):
// K/V LDS fragment reads shared across groups -> ~46% less LDS traffic per
// q-row, half the wave-tiles, same total MFMA.
// Block = 128 q-rows. Grid = 32 x 8 x 4 = 1024 blocks = 4/CU @ 40KB LDS.
// ---------------------------------------------------------------------------
__global__ __launch_bounds__(256) void flash_kernel(
    const unsigned short* __restrict__ Qhi, const unsigned short* __restrict__ Qlo,
    const unsigned short* __restrict__ Khi_g, const unsigned short* __restrict__ Klo_g,
    const unsigned short* __restrict__ Vt_g,
    unsigned short* __restrict__ Part, float2* __restrict__ ML)
{
    __shared__ __align__(16) char lds[24576];        // Khi 8K | Klo 8K | Vt 8K
    __shared__ __align__(16) unsigned short PS[4][2][16 * 64]; // [wave][group][row][key]

    const int h  = blockIdx.y;
    const int ks = blockIdx.z;
    const int q0 = blockIdx.x * 128;
    const int tid  = threadIdx.x;
    const int lane = tid & 63;
    const int w    = tid >> 6;
    const int l15  = lane & 15;
    const int lhi  = lane >> 4;

    // Q fragments (B-operand): col = l15 = qrow, k(d) = lhi*8 + 32c + j
    bf16x8 qh[2][2], ql[2][2];
#pragma unroll
    for (int g = 0; g < 2; ++g) {
        const int qrow = q0 + g * 64 + w * 16 + l15;
#pragma unroll
        for (int c = 0; c < 2; ++c) {
            size_t off = ((size_t)(h * S_LEN + qrow)) * D_DIM + lhi * 8 + 32 * c;
            qh[g][c] = *(const bf16x8*)&Qhi[off];
            ql[g][c] = *(const bf16x8*)&Qlo[off];
        }
    }

    // staging source pointers (pre-swizzled within 128B rows)
    const char *pKh[2], *pKl[2], *pV[2];
    int ldsd[2];
    {
        const int chunk = lane & 7;
#pragma unroll
        for (int i = 0; i < 2; ++i) {
            int r = w * 16 + i * 8 + (lane >> 3);
            int swz = (chunk * 16) ^ ((r & 7) << 4);
            size_t kb = ((size_t)(h * S_LEN + ks * (S_LEN / KSPLIT) + r)) * 128 + swz;
            pKh[i] = (const char*)Khi_g + kb;
            pKl[i] = (const char*)Klo_g + kb;
            size_t vb = ((size_t)(h * D_DIM + r) * S_LEN + ks * (S_LEN / KSPLIT)) * 2 + swz;
            pV[i] = (const char*)Vt_g + vb;
            ldsd[i] = (w * 16 + i * 8) * 128;
        }
    }

    f32x4 acc_o[2][4];
#pragma unroll
    for (int g = 0; g < 2; ++g)
#pragma unroll
        for (int nt = 0; nt < 4; ++nt) acc_o[g][nt] = (f32x4){0.f, 0.f, 0.f, 0.f};
    float m2[2] = {-1e30f, -1e30f};
    float lsum[2] = {0.f, 0.f};

    for (int kt = 0; kt < NKT; ++kt) {
        __syncthreads();
#pragma unroll
        for (int i = 0; i < 2; ++i) {
            gl_lds16(pKh[i], lds + ldsd[i]);
            gl_lds16(pKl[i], lds + 8192 + ldsd[i]);
            gl_lds16(pV[i],  lds + 16384 + ldsd[i]);
            pKh[i] += 8192; pKl[i] += 8192; pV[i] += 128;
        }
        __syncthreads();

        const char* Kh = lds;
        const char* Kl = lds + 8192;
        const char* Vl = lds + 16384;

        // ---- scores (exp2 domain): 3-term split MFMA, swapped (A=K, B=Q),
        // K fragments shared across both q-groups
        f32x4 sacc[2][4];
#pragma unroll
        for (int g = 0; g < 2; ++g)
#pragma unroll
            for (int nt = 0; nt < 4; ++nt) sacc[g][nt] = (f32x4){0.f, 0.f, 0.f, 0.f};
        __builtin_amdgcn_s_setprio(1);
#pragma unroll
        for (int c = 0; c < 2; ++c) {
            int colb = (lhi * 8 + 32 * c) * 2;
#pragma unroll
            for (int nt = 0; nt < 4; ++nt) {
                int key = l15 + 16 * nt;      // A row = key within tile
                int lo = key * 128 + (((colb >> 4) ^ (key & 7)) << 4);
                bf16x8 kh = *(const bf16x8*)(Kh + lo);
                bf16x8 kl = *(const bf16x8*)(Kl + lo);
#pragma unroll
                for (int g = 0; g < 2; ++g) {
                    sacc[g][nt] = mfma16(kh, qh[g][c], sacc[g][nt]);
                    sacc[g][nt] = mfma16(kl, qh[g][c], sacc[g][nt]);
                    sacc[g][nt] = mfma16(kh, ql[g][c], sacc[g][nt]);
                }
            }
        }
        __builtin_amdgcn_s_setprio(0);

        // ---- softmax per group (16 in-lane scores + 2 shfl)
#pragma unroll
        for (int g = 0; g < 2; ++g) {
            float mx0 = fmaxf(fmaxf(sacc[g][0][0], sacc[g][0][1]), fmaxf(sacc[g][0][2], sacc[g][0][3]));
            float mx1 = fmaxf(fmaxf(sacc[g][1][0], sacc[g][1][1]), fmaxf(sacc[g][1][2], sacc[g][1][3]));
            float mx2 = fmaxf(fmaxf(sacc[g][2][0], sacc[g][2][1]), fmaxf(sacc[g][2][2], sacc[g][2][3]));
            float mx3 = fmaxf(fmaxf(sacc[g][3][0], sacc[g][3][1]), fmaxf(sacc[g][3][2], sacc[g][3][3]));
            float vm = fmaxf(fmaxf(mx0, mx1), fmaxf(mx2, mx3));
            vm = fmaxf(vm, __shfl_xor(vm, 16));
            vm = fmaxf(vm, __shfl_xor(vm, 32));

            // T13 defer-rescale
            if (!__all(vm <= m2[g] + 8.f)) {
                float mnew = fmaxf(m2[g], vm);
                float sc = exp2f(m2[g] - mnew);
                m2[g] = mnew;
                lsum[g] *= sc;
                float scj[4];
#pragma unroll
                for (int j = 0; j < 4; ++j) scj[j] = __shfl(sc, lhi * 4 + j);
#pragma unroll
                for (int nt = 0; nt < 4; ++nt)
#pragma unroll
                    for (int j = 0; j < 4; ++j) acc_o[g][nt][j] *= scj[j];
            }

            float sum = 0.f;
            unsigned short* pw = &PS[w][g][0];
#pragma unroll
            for (int nt = 0; nt < 4; ++nt) {
                float e0 = exp2f(sacc[g][nt][0] - m2[g]);
                float e1 = exp2f(sacc[g][nt][1] - m2[g]);
                float e2 = exp2f(sacc[g][nt][2] - m2[g]);
                float e3 = exp2f(sacc[g][nt][3] - m2[g]);
                sum += (e0 + e1) + (e2 + e3);
                int colb = 32 * nt + 8 * lhi;
                int adr = l15 * 128 + ((((colb >> 4)) ^ (l15 & 7)) << 4) + (colb & 15);
                uint2 pk = make_uint2(cvtpk(e0, e1), cvtpk(e2, e3));
                *(uint2*)((char*)pw + adr) = pk;
            }
            sum += __shfl_xor(sum, 16);
            sum += __shfl_xor(sum, 32);
            lsum[g] += sum;
        }

        // ---- PV: V fragments shared across both q-groups
        __builtin_amdgcn_s_setprio(1);
#pragma unroll
        for (int c = 0; c < 2; ++c) {
            int colb = (lhi * 8 + 32 * c) * 2;
            int loA = l15 * 128 + (((colb >> 4) ^ (l15 & 7)) << 4);
            bf16x8 pa0 = *(const bf16x8*)((const char*)&PS[w][0][0] + loA);
            bf16x8 pa1 = *(const bf16x8*)((const char*)&PS[w][1][0] + loA);
#pragma unroll
            for (int nt = 0; nt < 4; ++nt) {
                int d = l15 + 16 * nt;
                int loB = d * 128 + (((colb >> 4) ^ (d & 7)) << 4);
                bf16x8 vb = *(const bf16x8*)(Vl + loB);
                acc_o[0][nt] = mfma16(pa0, vb, acc_o[0][nt]);
                acc_o[1][nt] = mfma16(pa1, vb, acc_o[1][nt]);
            }
        }
        __builtin_amdgcn_s_setprio(0);
    }

    // ---- epilogue: normalized bf16 partial + (m,l), per group
    unsigned short* PT = Part + ((size_t)(ks * H_NUM + h)) * S_LEN * D_DIM;
#pragma unroll
    for (int g = 0; g < 2; ++g) {
        if (lane < 16) {
            ML[(size_t)(ks * H_NUM + h) * S_LEN + q0 + g * 64 + w * 16 + l15] =
                make_float2(m2[g], lsum[g]);
        }
#pragma unroll
        for (int r = 0; r < 4; ++r) {
            float lr = __shfl(lsum[g], lhi * 4 + r);
            float inv = 1.f / lr;
            int s = q0 + g * 64 + w * 16 + lhi * 4 + r;
#pragma unroll
            for (int nt = 0; nt < 4; ++nt)
                PT[(size_t)s * D_DIM + l15 + 16 * nt] = f2bf(acc_o[g][nt][r] * inv);
        }
    }
}

// ---------------------------------------------------------------------------
// cw: per (h,s) combine weights c_i = l_i*2^(m_i-m) / L  (4 splits)
// ---------------------------------------------------------------------------
__global__ __launch_bounds__(256) void cw_kernel(
    const float2* __restrict__ ML, float4* __restrict__ CW)
{
    int i = blockIdx.x * 256 + threadIdx.x;   // H*S = 32768
    float2 a[KSPLIT];
    float m = -1e30f;
#pragma unroll
    for (int k = 0; k < KSPLIT; ++k) {
        a[k] = ML[(size_t)k * H_NUM * S_LEN + i];
        m = fmaxf(m, a[k].x);
    }
    float wk[KSPLIT], wsum = 0.f;
#pragma unroll
    for (int k = 0; k < KSPLIT; ++k) {
        wk[k] = exp2f(a[k].x - m) * a[k].y;
        wsum += wk[k];
    }
    float inv = 1.f / wsum;
    CW[i] = make_float4(wk[0] * inv, wk[1] * inv, wk[2] * inv, wk[3] * inv);
}

// ---------------------------------------------------------------------------
// zout: Z[4096,64] = combine(4 partials) [4096,512] @ W0[512,64], fp32.
// ---------------------------------------------------------------------------
__global__ __launch_bounds__(256) void zout_kernel(
    const unsigned short* __restrict__ Part, const float4* __restrict__ CW,
    const float* __restrict__ W0, float* __restrict__ Z)
{
    __shared__ __align__(16) float Rs[32][64];
    __shared__ __align__(16) float Ws[32][64];

    const size_t PSZ = (size_t)H_NUM * S_LEN * D_DIM;
    const int s0 = blockIdx.x * 64;
    const int tid = threadIdx.x;
    const int tx = tid & 15;
    const int ty = tid >> 4;

    float acc[4][4];
#pragma unroll
    for (int i = 0; i < 4; ++i)
#pragma unroll
        for (int j = 0; j < 4; ++j) acc[i][j] = 0.f;

    for (int kb = 0; kb < E_DIM; kb += 32) {
        __syncthreads();
#pragma unroll
        for (int p = 0; p < 2; ++p) {
            int idx = tid + 256 * p;
            int row = idx >> 3;
            int kq  = idx & 7;
            int k = kb + kq * 4;
            int hh = k >> 6, d0 = k & 63;
            int s = s0 + row;
            size_t pbase = ((size_t)hh * S_LEN + s) * D_DIM + d0;
            float4 c = *(const float4*)&CW[hh * S_LEN + s];
            u16x4 a0 = *(const u16x4*)&Part[pbase];
            u16x4 a1 = *(const u16x4*)&Part[PSZ + pbase];
            u16x4 a2 = *(const u16x4*)&Part[2 * PSZ + pbase];
            u16x4 a3 = *(const u16x4*)&Part[3 * PSZ + pbase];
#pragma unroll
            for (int j = 0; j < 4; ++j)
                Rs[kq * 4 + j][row] = bf2f(a0[j]) * c.x + bf2f(a1[j]) * c.y +
                                      bf2f(a2[j]) * c.z + bf2f(a3[j]) * c.w;
        }
#pragma unroll
        for (int p = 0; p < 2; ++p) {
            int idx = tid + 256 * p;
            int k  = idx >> 4;
            int nq = idx & 15;
            *(float4*)&Ws[k][nq * 4] = *(const float4*)&W0[(size_t)(kb + k) * D_DIM + nq * 4];
        }
        __syncthreads();

#pragma unroll 8
        for (int k = 0; k < 32; ++k) {
            float a[4], b[4];
            *(float4*)&a[0] = *(const float4*)&Rs[k][ty * 4];
            *(float4*)&b[0] = *(const float4*)&Ws[k][tx * 4];
#pragma unroll
            for (int i = 0; i < 4; ++i)
#pragma unroll
                for (int j = 0; j < 4; ++j) acc[i][j] += a[i] * b[j];
        }
    }

#pragma unroll
    for (int i = 0; i < 4; ++i) {
        float4 o = make_float4(acc[i][0], acc[i][1], acc[i][2], acc[i][3]);
        *(float4*)&Z[(size_t)(s0 + ty * 4 + i) * D_DIM + tx * 4] = o;
    }
}

// ---------------------------------------------------------------------------
extern "C" void kernel_launch(void* const* d_in, const int* in_sizes, int n_in,
                              void* d_out, int out_size, void* d_ws, size_t ws_size,
                              hipStream_t stream) {
    const float* X  = (const float*)d_in[0];
    const float* Wq = (const float*)d_in[1];
    const float* Wk = (const float*)d_in[2];
    const float* Wv = (const float*)d_in[3];
    const float* W0 = (const float*)d_in[4];

    char* ws = (char*)d_ws;
    const size_t MB = 1ull << 20;
    unsigned short* Qhi = (unsigned short*)(ws + 0 * MB);
    unsigned short* Qlo = (unsigned short*)(ws + 4 * MB);
    unsigned short* Khi = (unsigned short*)(ws + 8 * MB);
    unsigned short* Klo = (unsigned short*)(ws + 12 * MB);
    unsigned short* Vt  = (unsigned short*)(ws + 16 * MB);
    // phase-1 region (dead before flash writes Part):
    unsigned short* Xhi = (unsigned short*)(ws + 24 * MB);
    unsigned short* Xlo = (unsigned short*)(ws + 28 * MB);
    unsigned short* WT  = (unsigned short*)(ws + 32 * MB);   // 3 MB
    // phase-2 (aliases phase-1 region):
    unsigned short* Part = (unsigned short*)(ws + 20 * MB);  // 16 MB (4 splits)
    float2* ML = (float2*)(ws + 36 * MB);                    // 1 MB
    float4* CW = (float4*)(ws + 37 * MB);                    // 0.5 MB

    float* Z = (float*)d_out;

    prepass_kernel<<<dim3(2048 + 768), 256, 0, stream>>>(X, Wq, Wk, Wv, Xhi, Xlo, WT);
    proj_kernel<<<dim3(S_LEN / 128, 4, 3), 256, 0, stream>>>(
        Xhi, Xlo, WT, Qhi, Qlo, Khi, Klo, Vt);
    flash_kernel<<<dim3(S_LEN / 128, H_NUM, KSPLIT), 256, 0, stream>>>(
        Qhi, Qlo, Khi, Klo, Vt, Part, ML);
    cw_kernel<<<dim3(H_NUM * S_LEN / 256), 256, 0, stream>>>(ML, CW);
    zout_kernel<<<dim3(S_LEN / 64), 256, 0, stream>>>(Part, CW, W0, Z);
}